// Round 14
// baseline (76.646 us; speedup 1.0000x reference)
//
#include <hip/hip_runtime.h>
#include <math.h>

#define NN 50
#define E2 400
#define ET 450
#define NTHR 256
#define KL 8             // Lanczos iterations
#define QS 52            // sQ2 row stride
#define MS 68            // padded sMw2 row stride

// Intra-wave LDS handoff fence: drain LDS ops, forbid compiler reordering.
#define WSYNC() do { asm volatile("s_waitcnt lgkmcnt(0)" ::: "memory"); \
                     __builtin_amdgcn_sched_barrier(0); } while (0)

__global__ __launch_bounds__(NTHR, 1) void opn_kernel(
    const float* __restrict__ gx, const int* __restrict__ gedge,
    const float* __restrict__ gmask,
    const float* __restrict__ w1, const float* __restrict__ as1,
    const float* __restrict__ ad1, const float* __restrict__ b1,
    const float* __restrict__ w2, const float* __restrict__ as2,
    const float* __restrict__ ad2, const float* __restrict__ b2,
    const float* __restrict__ miw, const float* __restrict__ mib,
    const float* __restrict__ mow, const float* __restrict__ mob,
    const float* __restrict__ wq, const float* __restrict__ bq,
    const float* __restrict__ wk, const float* __restrict__ bk,
    const float* __restrict__ wv, const float* __restrict__ bv,
    const float* __restrict__ ws, const float* __restrict__ bs,
    const float* __restrict__ mw1, const float* __restrict__ mb1,
    const float* __restrict__ mw2, const float* __restrict__ mb2,
    const float* __restrict__ cw, const float* __restrict__ cb,
    float* __restrict__ out)
{
    const int tid = threadIdx.x;

    __shared__ alignas(16) float sS[3200];           // GAT1 h8 -> MLP hid64
    __shared__ alignas(16) float sQ2[(KL + 2) * QS]; // Lanczos vectors (rows 1..KL)
    __shared__ float sZ[64];         // dis-scaled q (matvec operand)
    __shared__ float sAl_[KL + 2];
    __shared__ float sBe_[KL + 2];
    __shared__ float sY[KL + 2];
    __shared__ float sCp[KL + 2];
    __shared__ float sDp2[KL + 2];
    __shared__ float sB5h[NN * 5];   // GAT2 h5
    __shared__ alignas(16) float sKV[NN * 16];  // MHA k@0-4, v@8-12
    __shared__ alignas(16) float sTKV[NN * 16]; // TC  k@0-4, v@8-12
    __shared__ float sTo[NN * 5];    // TC out
    __shared__ int   sSrc[ET];
    __shared__ int   sDst[ET];
    __shared__ int   sSrcCsr[ET];
    __shared__ float sAs[NN];        // GAT1 src coeffs
    __shared__ float sAsB[NN];       // GAT2 src coeffs
    __shared__ float sred[4];
    __shared__ int   sOff[NN + 1];
    // staged weights (filled by waves 2-3)
    __shared__ float sW1[40], sAs1[8], sAd1[8], sB1[8];
    __shared__ float sW2[40], sAs2[5], sAd2[5], sB2[5];
    __shared__ float sMiw[75], sMib[15], sMow[25], sMob[5];
    __shared__ float sWq[25], sBq[5], sWk[25], sBk[5];
    __shared__ float sWv[25], sBv[5], sWsk[25], sBsk[5];
    __shared__ float sMw1[320], sMb1[64];
    __shared__ alignas(16) float sMw2[NN * MS];
    __shared__ float sMb2[NN], sCw[NN], sCb0[1], sMask[NN];

    const float inv_sqrt5 = 0.4472135954999579f;
    float xr0 = 0, xr1 = 0, xr2 = 0, xr3 = 0, xr4 = 0;   // x_combined row (wave 0)

    // ======== parallel section ========
    if (tid < 64) {
        // wave 0: just fetch gx; everything else waits on wave 1's CSR
        int gi = (tid < NN) ? tid : NN - 1;
        xr0 = gx[gi * 3 + 0]; xr1 = gx[gi * 3 + 1]; xr2 = gx[gi * 3 + 2];
    } else if (tid < 128) {
        // wave 1: edges, counts (regs), prefix scan, CSR scatter, ei out
        const int l = tid - 64;
        for (int t = l; t < ET; t += 64) {
            int s, d;
            if (t < E2) { s = gedge[t]; d = gedge[E2 + t]; }
            else        { s = t - E2;   d = t - E2; }
            sSrc[t] = s; sDst[t] = d;
        }
        WSYNC();
        int cnt = 0;
        if (l < NN)
            for (int e = 0; e < ET; ++e) cnt += (sDst[e] == l) ? 1 : 0;
        int inc = cnt;
#pragma unroll
        for (int off = 1; off < 64; off <<= 1) {
            int n = __shfl_up(inc, off);
            if (l >= off) inc += n;
        }
        int exc = inc - cnt;
        if (l < NN) sOff[l] = exc;
        if (l == NN - 1) sOff[NN] = inc;
        if (l < NN) {
            int pos = exc;
            for (int e = 0; e < ET; ++e)
                if (sDst[e] == l) { sSrcCsr[pos] = sSrc[e]; ++pos; }
        }
        for (int t = l; t < 2 * ET; t += 64) {
            int val = (t < ET) ? sSrc[t] : sDst[t - ET];
            out[2751 + t] = (float)val;
        }
    } else {
        // waves 2-3: staging (issue all loads, then store)
        const int t0 = tid - 128;
        float vW1  = w1 [t0 < 40 ? t0 : 39];
        float vAs1 = as1[t0 < 8  ? t0 : 7];
        float vAd1 = ad1[t0 < 8  ? t0 : 7];
        float vB1  = b1 [t0 < 8  ? t0 : 7];
        float vW2  = w2 [t0 < 40 ? t0 : 39];
        float vAs2 = as2[t0 < 5  ? t0 : 4];
        float vAd2 = ad2[t0 < 5  ? t0 : 4];
        float vB2  = b2 [t0 < 5  ? t0 : 4];
        float vMiw = miw[t0 < 75 ? t0 : 74];
        float vMib = mib[t0 < 15 ? t0 : 14];
        float vMow = mow[t0 < 25 ? t0 : 24];
        float vMob = mob[t0 < 5  ? t0 : 4];
        float vWq  = wq [t0 < 25 ? t0 : 24];
        float vBq  = bq [t0 < 5  ? t0 : 4];
        float vWk  = wk [t0 < 25 ? t0 : 24];
        float vBk  = bk [t0 < 5  ? t0 : 4];
        float vWv  = wv [t0 < 25 ? t0 : 24];
        float vBv  = bv [t0 < 5  ? t0 : 4];
        float vWs  = ws [t0 < 25 ? t0 : 24];
        float vBs  = bs [t0 < 5  ? t0 : 4];
        float vMb1 = mb1[t0 < 64 ? t0 : 63];
        float vMb2 = mb2[t0 < NN ? t0 : NN - 1];
        float vCw  = cw [t0 < NN ? t0 : NN - 1];
        float vCb  = cb[0];
        float vMsk = gmask[t0 < NN ? t0 : NN - 1];
        int ta = t0, tb2 = t0 + 128, tc = (t0 + 256 < 320) ? t0 + 256 : 319;
        float vM1a = mw1[(ta  / 5) * 250 + (ta  % 5)];
        float vM1b = mw1[(tb2 / 5) * 250 + (tb2 % 5)];
        float vM1c = mw1[(tc  / 5) * 250 + (tc  % 5)];
        const float4* m2 = (const float4*)mw2;
        float4 v2[7];
#pragma unroll
        for (int u = 0; u < 7; ++u) {
            int t = t0 + u * 128;
            v2[u] = m2[t < 800 ? t : 799];
        }
        if (t0 < 40) sW1[t0]  = vW1;
        if (t0 < 8)  { sAs1[t0] = vAs1; sAd1[t0] = vAd1; sB1[t0] = vB1; }
        if (t0 < 40) sW2[t0]  = vW2;
        if (t0 < 5)  { sAs2[t0] = vAs2; sAd2[t0] = vAd2; sB2[t0] = vB2; }
        if (t0 < 75) sMiw[t0] = vMiw;
        if (t0 < 15) sMib[t0] = vMib;
        if (t0 < 25) { sMow[t0] = vMow; sWq[t0] = vWq; sWk[t0] = vWk;
                       sWv[t0] = vWv;  sWsk[t0] = vWs; }
        if (t0 < 5)  { sMob[t0] = vMob; sBq[t0] = vBq; sBk[t0] = vBk;
                       sBv[t0] = vBv;  sBsk[t0] = vBs; }
        if (t0 < 64) sMb1[t0] = vMb1;
        if (t0 < NN) { sMb2[t0] = vMb2; sCw[t0] = vCw; sMask[t0] = vMsk; }
        if (t0 == 0) sCb0[0] = vCb;
        sMw1[ta]  = vM1a;
        sMw1[tb2] = vM1b;
        if (t0 + 256 < 320) sMw1[t0 + 256] = vM1c;
#pragma unroll
        for (int u = 0; u < 7; ++u) {
            int t = t0 + u * 128;
            if (t < 800) {
                int o = t >> 4, k4 = t & 15;
                *(float4*)&sMw2[o * MS + k4 * 4] = v2[u];
            }
        }
    }
    __syncthreads();   // join: CSR + weights visible to wave 0

    // ==== wave 0: CSR-sparse eigensolver + fused GNN tail ====
    if (tid < 64) {
        const int lane = tid;
        const int c0 = (lane < NN) ? sOff[lane] : 0;
        const int c1 = (lane < NN) ? sOff[lane + 1] : 0;
        const int c1m1 = c1 - 1;                 // real edges (self-loop is last)
        const float deg = (float)(c1m1 - c0);    // in-degree = row sum (symmetric A)
        const float disl = (deg > 0.0f) ? rsqrtf(fmaxf(deg, 1e-12f)) : 0.0f;

        // ---- u0 normalize + deterministic q1 ----
        float q0r, qprev = 0.0f, qcur;
        {
            float q0 = (lane < NN) ? sqrtf(deg) : 0.0f;
            float nn = q0 * q0;
            for (int off = 32; off > 0; off >>= 1) nn += __shfl_xor(nn, off);
            q0 *= rsqrtf(nn);
            unsigned u = (unsigned)lane * 2654435761u + 12345u;
            u ^= u >> 13; u *= 2246822519u; u ^= u >> 11;
            float q1 = (lane < NN) ? ((float)(u & 0xFFFF) * (1.0f / 65536.0f) - 0.5f) : 0.0f;
            for (int pass = 0; pass < 2; ++pass) {
                float d = q0 * q1;
                for (int off = 32; off > 0; off >>= 1) d += __shfl_xor(d, off);
                q1 -= d * q0;
            }
            float n1 = q1 * q1;
            for (int off = 32; off > 0; off >>= 1) n1 += __shfl_xor(n1, off);
            q1 *= rsqrtf(n1);
            q0r = q0; qcur = q1;
            if (lane < NN) sQ2[QS + lane] = q1;
        }
        // ---- 3-term Lanczos, sparse matvec: w = q + dis*(A (dis*q)) ----
        int keffr = KL;
        for (int j = 1; j <= KL; ++j) {
            sZ[lane] = (lane < NN) ? disl * qcur : 0.0f;
            WSYNC();
            float w = 0.0f;
            if (lane < NN) {
                float g = 0.0f;
                int c = c0;
                for (; c + 4 <= c1m1; c += 4) {
                    int s0 = sSrcCsr[c],     s1 = sSrcCsr[c + 1];
                    int s2 = sSrcCsr[c + 2], s3 = sSrcCsr[c + 3];
                    g += (sZ[s0] + sZ[s1]) + (sZ[s2] + sZ[s3]);
                }
                for (; c < c1m1; ++c) g += sZ[sSrcCsr[c]];
                w = qcur + disl * g;
            }
            float cc0 = q0r * w, cc1 = qprev * w, ca = qcur * w;
#pragma unroll
            for (int off = 32; off > 0; off >>= 1) {
                cc0 += __shfl_xor(cc0, off);
                cc1 += __shfl_xor(cc1, off);
                ca  += __shfl_xor(ca, off);
            }
            w -= cc0 * q0r + cc1 * qprev + ca * qcur;
            float nn2 = w * w;
#pragma unroll
            for (int off = 32; off > 0; off >>= 1) nn2 += __shfl_xor(nn2, off);
            float beta = sqrtf(nn2);
            if (lane == 0) { sAl_[j] = ca; sBe_[j] = beta; }
            if (j < KL) {
                if (beta > 1e-10f) {
                    qprev = qcur;
                    qcur = w * (1.0f / beta);
                    if (lane < NN) sQ2[(j + 1) * QS + lane] = qcur;
                } else { keffr = j; break; }     // beta lane-uniform
            }
        }
        WSYNC();
        // ---- extraction: bisection + Thomas + Fiedler ----
        const int keff = keffr;
        float lo = 1e30f, hi = -1e30f;
        for (int m = 1; m <= keff; ++m) {
            float r = ((m > 1) ? fabsf(sBe_[m - 1]) : 0.0f)
                    + ((m < keff) ? fabsf(sBe_[m]) : 0.0f);
            lo = fminf(lo, sAl_[m] - r);
            hi = fmaxf(hi, sAl_[m] + r);
        }
        for (int round = 0; round < 4; ++round) {
            float h = (hi - lo) * (1.0f / 65.0f);
            float x = lo + (float)(lane + 1) * h;
            int cnt = 0;
            float d = sAl_[1] - x;
            if (d < 0.0f) cnt++;
            for (int m = 2; m <= keff; ++m) {
                float b = sBe_[m - 1];
                float dd = (fabsf(d) < 1e-20f) ? ((d >= 0.0f) ? 1e-20f : -1e-20f) : d;
                d = sAl_[m] - x - b * b / dd;
                if (d < 0.0f) cnt++;
            }
            unsigned long long msk = __ballot(cnt >= keff);
            int f = (msk == 0ULL) ? 64 : (__ffsll((unsigned long long)msk) - 1);
            float nlo = (f == 0) ? lo : (lo + (float)f * h);
            float nhi = (f == 64) ? hi : (lo + (float)(f + 1) * h);
            lo = nlo; hi = nhi;
        }
        const float th = 0.5f * (lo + hi);
        if (lane == 0) {
            if (keff == 1) {
                sY[1] = 1.0f;
            } else {
                float inv0 = rsqrtf((float)keff);
                for (int m = 1; m <= keff; ++m) sY[m] = inv0;
                float d1 = sAl_[1] - th;
                if (fabsf(d1) < 1e-10f) d1 = (d1 >= 0.0f) ? 1e-10f : -1e-10f;
                sCp[1] = sBe_[1] / d1;
                sDp2[1] = sY[1] / d1;
                for (int m = 2; m <= keff; ++m) {
                    float den = sAl_[m] - th - sBe_[m - 1] * sCp[m - 1];
                    if (fabsf(den) < 1e-10f) den = (den >= 0.0f) ? 1e-10f : -1e-10f;
                    if (m < keff) sCp[m] = sBe_[m] / den;
                    sDp2[m] = (sY[m] - sBe_[m - 1] * sDp2[m - 1]) / den;
                }
                sY[keff] = sDp2[keff];
                for (int m = keff - 1; m >= 1; --m)
                    sY[m] = sDp2[m] - sCp[m] * sY[m + 1];
                float nn = 0.0f;
                for (int m = 1; m <= keff; ++m) nn += sY[m] * sY[m];
                float sc = rsqrtf(nn);
                for (int m = 1; m <= keff; ++m) sY[m] *= sc;
            }
        }
        WSYNC();
        float v = 0.0f;
        if (lane < NN)
            for (int m = 1; m <= keff; ++m) v += sY[m] * sQ2[m * QS + lane];
        {
            float nn = v * v;
            for (int off = 32; off > 0; off >>= 1) nn += __shfl_xor(nn, off);
            float av = fabsf(v);
            for (int off = 32; off > 0; off >>= 1) av = fmaxf(av, __shfl_xor(av, off));
            unsigned long long msk = __ballot((fabsf(v) == av) && (lane < NN));
            int fl = __ffsll((unsigned long long)msk) - 1;
            float sv = __shfl(v, fl);
            v *= ((sv >= 0.0f) ? 1.0f : -1.0f) * rsqrtf(nn);
        }
        xr3 = q0r; xr4 = v;
        if (lane < NN) {
            out[2501 + lane * 5 + 0] = xr0;
            out[2501 + lane * 5 + 1] = xr1;
            out[2501 + lane * 5 + 2] = xr2;
            out[2501 + lane * 5 + 3] = xr3;
            out[2501 + lane * 5 + 4] = xr4;
        }

        float* h8 = sS;
        // ---- P0: GAT1 linear + src coeff ----
        float adl = 0.0f;
        if (lane < NN) {
            float a = 0.0f;
#pragma unroll
            for (int o = 0; o < 8; ++o) {
                float acc = xr0 * sW1[o * 5 + 0] + xr1 * sW1[o * 5 + 1]
                          + xr2 * sW1[o * 5 + 2] + xr3 * sW1[o * 5 + 3]
                          + xr4 * sW1[o * 5 + 4];
                h8[lane * 8 + o] = acc;
                a   += acc * sAs1[o];
                adl += acc * sAd1[o];
            }
            sAs[lane] = a;
        }
        WSYNC();
        // ---- P1: GAT1 fused score+softmax+agg + GAT2 linear ----
        float adlB = 0.0f;
        if (lane < NN) {
            float su = 0.0f;
            float acc[8] = {0, 0, 0, 0, 0, 0, 0, 0};
            for (int c = c0; c < c1; ++c) {
                const int s2 = sSrcCsr[c];
                float sc = sAs[s2] + adl;
                sc = (sc > 0.0f) ? sc : 0.2f * sc;
                float p = __expf(sc);
                su += p;
                const float* hp = &h8[s2 * 8];
#pragma unroll
                for (int o = 0; o < 8; ++o) acc[o] += p * hp[o];
            }
            float inv = 1.0f / (su + 1e-16f);
            float o8r[8];
#pragma unroll
            for (int o = 0; o < 8; ++o) o8r[o] = fmaxf(sB1[o] + acc[o] * inv, 0.0f);
            float aB = 0.0f;
#pragma unroll
            for (int o = 0; o < 5; ++o) {
                float a2 = 0.0f;
#pragma unroll
                for (int k = 0; k < 8; ++k) a2 += o8r[k] * sW2[o * 8 + k];
                sB5h[lane * 5 + o] = a2;
                aB   += a2 * sAs2[o];
                adlB += a2 * sAd2[o];
            }
            sAsB[lane] = aB;
        }
        WSYNC();
        // ---- P2: GAT2 fused agg + MHA in-proj (packed k/v) ----
        float qr[5];
        if (lane < NN) {
            float su = 0.0f;
            float acc[5] = {0, 0, 0, 0, 0};
            for (int c = c0; c < c1; ++c) {
                const int s2 = sSrcCsr[c];
                float sc = sAsB[s2] + adlB;
                sc = (sc > 0.0f) ? sc : 0.2f * sc;
                float p = __expf(sc);
                su += p;
                const float* hp = &sB5h[s2 * 5];
#pragma unroll
                for (int o = 0; o < 5; ++o) acc[o] += p * hp[o];
            }
            float inv = 1.0f / (su + 1e-16f);
            float hr[5];
#pragma unroll
            for (int o = 0; o < 5; ++o) hr[o] = sB2[o] + acc[o] * inv;
#pragma unroll
            for (int o = 0; o < 5; ++o) {
                float q_ = sMib[o], k_ = sMib[o + 5], v_ = sMib[o + 10];
#pragma unroll
                for (int k = 0; k < 5; ++k) {
                    q_ += hr[k] * sMiw[o * 5 + k];
                    k_ += hr[k] * sMiw[(o + 5) * 5 + k];
                    v_ += hr[k] * sMiw[(o + 10) * 5 + k];
                }
                qr[o] = q_;
                sKV[lane * 16 + o]     = k_;
                sKV[lane * 16 + 8 + o] = v_;
            }
        }
        WSYNC();
        // ---- P3: MHA single-pass attn (float4 packed reads) + TC linear ----
        float tq[5], skip[5];
        if (lane < NN) {
            float su = 0.0f;
            float a5[5] = {0, 0, 0, 0, 0};
            for (int j = 0; j < NN; ++j) {
                const float* row = &sKV[j * 16];
                float4 k4 = *(const float4*)row;
                float  kk = row[4];
                float d = qr[0] * k4.x + qr[1] * k4.y + qr[2] * k4.z
                        + qr[3] * k4.w + qr[4] * kk;
                float p = __expf(d * inv_sqrt5);
                su += p;
                float4 v4 = *(const float4*)(row + 8);
                float  vv = row[12];
                a5[0] += p * v4.x; a5[1] += p * v4.y; a5[2] += p * v4.z;
                a5[3] += p * v4.w; a5[4] += p * vv;
            }
            float inv = 1.0f / su;
#pragma unroll
            for (int f = 0; f < 5; ++f) a5[f] *= inv;
            float hm[5];
#pragma unroll
            for (int o = 0; o < 5; ++o) {
                float acc = sMob[o];
#pragma unroll
                for (int k = 0; k < 5; ++k) acc += a5[k] * sMow[o * 5 + k];
                hm[o] = acc;
            }
#pragma unroll
            for (int o = 0; o < 5; ++o) {
                float q_ = sBq[o], k_ = sBk[o], v_ = sBv[o], s_ = sBsk[o];
#pragma unroll
                for (int k = 0; k < 5; ++k) {
                    q_ += hm[k] * sWq[o * 5 + k];
                    k_ += hm[k] * sWk[o * 5 + k];
                    v_ += hm[k] * sWv[o * 5 + k];
                    s_ += hm[k] * sWsk[o * 5 + k];
                }
                tq[o] = q_;
                sTKV[lane * 16 + o]     = k_;
                sTKV[lane * 16 + 8 + o] = v_;
                skip[o] = s_;
            }
        }
        WSYNC();
        // ---- P4: TC fused score+softmax+agg + skip (packed reads) ----
        if (lane < NN) {
            float su = 0.0f;
            float acc[5] = {0, 0, 0, 0, 0};
            for (int c = c0; c < c1; ++c) {
                const int s2 = sSrcCsr[c];
                const float* row = &sTKV[s2 * 16];
                float4 k4 = *(const float4*)row;
                float  kk = row[4];
                float d = tq[0] * k4.x + tq[1] * k4.y + tq[2] * k4.z
                        + tq[3] * k4.w + tq[4] * kk;
                float p = __expf(d * inv_sqrt5);
                su += p;
                float4 v4 = *(const float4*)(row + 8);
                float  vv = row[12];
                acc[0] += p * v4.x; acc[1] += p * v4.y; acc[2] += p * v4.z;
                acc[3] += p * v4.w; acc[4] += p * vv;
            }
            float inv = 1.0f / (su + 1e-16f);
#pragma unroll
            for (int o = 0; o < 5; ++o) sTo[lane * 5 + o] = skip[o] + acc[o] * inv;
        }
        WSYNC();
        // ---- P5: MLP1 (lane = hidden unit) ----
        {
            float wv5[5];
#pragma unroll
            for (int k = 0; k < 5; ++k) wv5[k] = sMw1[lane * 5 + k];
            const float bo = sMb1[lane];
            for (int i = 0; i < NN; ++i) {
                float acc = bo;
#pragma unroll
                for (int k = 0; k < 5; ++k) acc += sTo[i * 5 + k] * wv5[k];
                sS[i * 64 + lane] = fmaxf(acc, 0.0f);
            }
        }
    }
    __syncthreads();

    // ---------------- MLP2 + fused critic (4 waves) ----------------
    float part = 0.0f;
    for (int t = tid; t < NN * NN; t += NTHR) {
        int i = t / NN, j = t - i * NN;
        const float4* sp4 = (const float4*)&sS[i * 64];
        const float4* wp4 = (const float4*)&sMw2[j * MS];
        float a0 = 0.0f, a1 = 0.0f, a2 = 0.0f, a3 = 0.0f;
        for (int k = 0; k < 16; ++k) {
            float4 a = sp4[k], b = wp4[k];
            a0 += a.x * b.x; a1 += a.y * b.y;
            a2 += a.z * b.z; a3 += a.w * b.w;
        }
        float acc = sMb2[j] + (a0 + a1) + (a2 + a3);
        out[t] = acc * sMask[j];
        part += acc * sCw[j];
    }
    for (int off = 32; off > 0; off >>= 1) part += __shfl_xor(part, off);
    if ((tid & 63) == 0) sred[tid >> 6] = part;
    __syncthreads();
    if (tid == 0)
        out[2500] = (sred[0] + sred[1] + sred[2] + sred[3]) * (1.0f / NN) + sCb0[0];
}

extern "C" void kernel_launch(void* const* d_in, const int* in_sizes, int n_in,
                              void* d_out, int out_size, void* d_ws, size_t ws_size,
                              hipStream_t stream) {
    (void)in_sizes; (void)n_in; (void)d_ws; (void)ws_size; (void)out_size;
    opn_kernel<<<1, NTHR, 0, stream>>>(
        (const float*)d_in[0], (const int*)d_in[1], (const float*)d_in[2],
        (const float*)d_in[3], (const float*)d_in[4], (const float*)d_in[5], (const float*)d_in[6],
        (const float*)d_in[7], (const float*)d_in[8], (const float*)d_in[9], (const float*)d_in[10],
        (const float*)d_in[11], (const float*)d_in[12], (const float*)d_in[13], (const float*)d_in[14],
        (const float*)d_in[15], (const float*)d_in[16], (const float*)d_in[17], (const float*)d_in[18],
        (const float*)d_in[19], (const float*)d_in[20], (const float*)d_in[21], (const float*)d_in[22],
        (const float*)d_in[23], (const float*)d_in[24], (const float*)d_in[25], (const float*)d_in[26],
        (const float*)d_in[27], (const float*)d_in[28],
        (float*)d_out);
}

// Round 15
// 62.781 us; speedup vs baseline: 1.2209x; 1.2209x over previous
//
#include <hip/hip_runtime.h>
#include <math.h>

#define NN 50
#define E2 400
#define ET 450
#define NTHR 256
#define KL 8             // Lanczos iterations
#define QS 52            // padded row stride (16B-aligned rows)
#define MS 68            // padded sMw2 row stride

// Intra-wave LDS handoff fence: drain LDS ops, forbid compiler reordering.
#define WSYNC() do { asm volatile("s_waitcnt lgkmcnt(0)" ::: "memory"); \
                     __builtin_amdgcn_sched_barrier(0); } while (0)

__global__ __launch_bounds__(NTHR, 1) void opn_kernel(
    const float* __restrict__ gx, const int* __restrict__ gedge,
    const float* __restrict__ gmask,
    const float* __restrict__ w1, const float* __restrict__ as1,
    const float* __restrict__ ad1, const float* __restrict__ b1,
    const float* __restrict__ w2, const float* __restrict__ as2,
    const float* __restrict__ ad2, const float* __restrict__ b2,
    const float* __restrict__ miw, const float* __restrict__ mib,
    const float* __restrict__ mow, const float* __restrict__ mob,
    const float* __restrict__ wq, const float* __restrict__ bq,
    const float* __restrict__ wk, const float* __restrict__ bk,
    const float* __restrict__ wv, const float* __restrict__ bv,
    const float* __restrict__ ws, const float* __restrict__ bs,
    const float* __restrict__ mw1, const float* __restrict__ mb1,
    const float* __restrict__ mw2, const float* __restrict__ mb2,
    const float* __restrict__ cw, const float* __restrict__ cb,
    float* __restrict__ out)
{
    const int tid = threadIdx.x;

    __shared__ alignas(16) float sM[NN * NN];        // adjacency counts
    __shared__ alignas(16) float sS[3200];           // GAT1 h8 -> MLP hid64
    __shared__ alignas(16) float sL[NN * QS];        // padded Laplacian
    __shared__ alignas(16) float sQ2[(KL + 2) * QS]; // Lanczos vectors
    __shared__ float sAl_[KL + 2];
    __shared__ float sBe_[KL + 2];
    __shared__ float sY[KL + 2];
    __shared__ float sCp[KL + 2];
    __shared__ float sDp2[KL + 2];
    __shared__ float sB5h[NN * 5];   // GAT2 h5
    __shared__ alignas(16) float sKV[NN * 16];  // MHA k@0-4, v@8-12
    __shared__ alignas(16) float sTKV[NN * 16]; // TC  k@0-4, v@8-12
    __shared__ float sTo[NN * 5];    // TC out
    __shared__ int   sSrc[ET];
    __shared__ int   sDst[ET];
    __shared__ int   sSrcCsr[ET];
    __shared__ float sAs[NN];        // GAT1 src coeffs
    __shared__ float sAsB[NN];       // GAT2 src coeffs
    __shared__ float sdis[NN];
    __shared__ float sred[4];
    __shared__ int   sOff[NN + 1];
    // staged weights (filled by waves 2-3)
    __shared__ float sW1[40], sAs1[8], sAd1[8], sB1[8];
    __shared__ float sW2[40], sAs2[5], sAd2[5], sB2[5];
    __shared__ float sMiw[75], sMib[15], sMow[25], sMob[5];
    __shared__ float sWq[25], sBq[5], sWk[25], sBk[5];
    __shared__ float sWv[25], sBv[5], sWsk[25], sBsk[5];
    __shared__ float sMw1[320], sMb1[64];
    __shared__ alignas(16) float sMw2[NN * MS];
    __shared__ float sMb2[NN], sCw[NN], sCb0[1], sMask[NN];

    const float inv_sqrt5 = 0.4472135954999579f;
    float xr0 = 0, xr1 = 0, xr2 = 0, xr3 = 0, xr4 = 0;   // x_combined row (wave 0)
    int keffr = KL;

    // ======== parallel section: zero shared barriers ========
    if (tid < 64) {
        // -------- wave 0: adjacency -> Laplacian -> Lanczos -> extraction ----
        const int lane = tid;
        {   // early global loads
            int gi = (lane < NN) ? lane : NN - 1;
            xr0 = gx[gi * 3 + 0]; xr1 = gx[gi * 3 + 1]; xr2 = gx[gi * 3 + 2];
        }
        int es[7], ed[7];
#pragma unroll
        for (int u = 0; u < 7; ++u) {
            int e = lane + u * 64;
            int ec = (e < E2) ? e : E2 - 1;
            es[u] = gedge[ec]; ed[u] = gedge[E2 + ec];
        }
        for (int t = lane; t < NN * NN; t += 64) sM[t] = 0.0f;
        WSYNC();
#pragma unroll
        for (int u = 0; u < 7; ++u) {
            int e = lane + u * 64;
            if (e < E2) atomicAdd(&sM[es[u] * NN + ed[u]], 1.0f);
        }
        WSYNC();
        float dsum = 0.0f;
        if (lane < NN) {
            const float* rp = &sM[lane * NN];
#pragma unroll 5
            for (int k = 0; k < NN; ++k) dsum += rp[k];
        }
        float disl = (dsum > 0.0f) ? (1.0f / sqrtf(fmaxf(dsum, 1e-12f))) : 0.0f;
        if (lane < NN) sdis[lane] = disl;
        WSYNC();
        for (int t = lane; t < NN * QS; t += 64) {
            int i = t / QS, k = t - i * QS;
            sL[t] = (k < NN)
                  ? (((i == k) ? 1.0f : 0.0f) - sdis[i] * sM[i * NN + k] * sdis[k])
                  : 0.0f;
        }
        // u0 normalize + deterministic q1
        float q0r, qprev = 0.0f, qcur;
        {
            float q0 = (lane < NN) ? sqrtf(dsum) : 0.0f;
            float nn = q0 * q0;
            for (int off = 32; off > 0; off >>= 1) nn += __shfl_xor(nn, off);
            q0 *= rsqrtf(nn);
            unsigned u = (unsigned)lane * 2654435761u + 12345u;
            u ^= u >> 13; u *= 2246822519u; u ^= u >> 11;
            float q1 = (lane < NN) ? ((float)(u & 0xFFFF) * (1.0f / 65536.0f) - 0.5f) : 0.0f;
            for (int pass = 0; pass < 2; ++pass) {
                float d = q0 * q1;
                for (int off = 32; off > 0; off >>= 1) d += __shfl_xor(d, off);
                q1 -= d * q0;
            }
            float n1 = q1 * q1;
            for (int off = 32; off > 0; off >>= 1) n1 += __shfl_xor(n1, off);
            q1 *= rsqrtf(n1);
            q0r = q0; qcur = q1;
            if (lane < NN) { sQ2[lane] = q0; sQ2[QS + lane] = q1; }
            WSYNC();          // sL + q rows visible before matvec
        }
        // -------- 3-term Lanczos on B = 2I - L (dense float4 matvec) --------
        for (int j = 1; j <= KL; ++j) {
            const float* qp = &sQ2[j * QS];
            const float4* qp4 = (const float4*)qp;
            float w = 0.0f;
            if (lane < NN) {
                const float* rp = &sL[lane * QS];
                const float4* rp4 = (const float4*)rp;
                float a0 = 0.0f, a1 = 0.0f, a2 = 0.0f, a3 = 0.0f;
                for (int k = 0; k < 12; ++k) {
                    float4 r = rp4[k], q = qp4[k];
                    a0 += r.x * q.x; a1 += r.y * q.y;
                    a2 += r.z * q.z; a3 += r.w * q.w;
                }
                a0 += rp[48] * qp[48];
                a1 += rp[49] * qp[49];
                w = 2.0f * qcur - (a0 + a1 + a2 + a3);
            }
            float c0 = q0r * w, c1 = qprev * w, ca = qcur * w;
#pragma unroll
            for (int off = 32; off > 0; off >>= 1) {
                c0 += __shfl_xor(c0, off);
                c1 += __shfl_xor(c1, off);
                ca += __shfl_xor(ca, off);
            }
            w -= c0 * q0r + c1 * qprev + ca * qcur;
            float nn2 = w * w;
#pragma unroll
            for (int off = 32; off > 0; off >>= 1) nn2 += __shfl_xor(nn2, off);
            float beta = sqrtf(nn2);
            if (lane == 0) { sAl_[j] = ca; sBe_[j] = beta; }
            if (j < KL) {
                if (beta > 1e-10f) {
                    qprev = qcur;
                    qcur = w * (1.0f / beta);
                    if (lane < NN) sQ2[(j + 1) * QS + lane] = qcur;
                    WSYNC();
                } else { keffr = j; break; }     // beta lane-uniform
            }
        }
        WSYNC();
        // -------- extraction: bisection + Thomas + Fiedler --------
        const int keff = keffr;
        float lo = 1e30f, hi = -1e30f;
        for (int m = 1; m <= keff; ++m) {
            float r = ((m > 1) ? fabsf(sBe_[m - 1]) : 0.0f)
                    + ((m < keff) ? fabsf(sBe_[m]) : 0.0f);
            lo = fminf(lo, sAl_[m] - r);
            hi = fmaxf(hi, sAl_[m] + r);
        }
        for (int round = 0; round < 4; ++round) {
            float h = (hi - lo) * (1.0f / 65.0f);
            float x = lo + (float)(lane + 1) * h;
            int cnt = 0;
            float d = sAl_[1] - x;
            if (d < 0.0f) cnt++;
            for (int m = 2; m <= keff; ++m) {
                float b = sBe_[m - 1];
                float dd = (fabsf(d) < 1e-20f) ? ((d >= 0.0f) ? 1e-20f : -1e-20f) : d;
                d = sAl_[m] - x - b * b / dd;
                if (d < 0.0f) cnt++;
            }
            unsigned long long msk = __ballot(cnt >= keff);
            int f = (msk == 0ULL) ? 64 : (__ffsll((unsigned long long)msk) - 1);
            float nlo = (f == 0) ? lo : (lo + (float)f * h);
            float nhi = (f == 64) ? hi : (lo + (float)(f + 1) * h);
            lo = nlo; hi = nhi;
        }
        const float th = 0.5f * (lo + hi);
        if (lane == 0) {
            if (keff == 1) {
                sY[1] = 1.0f;
            } else {
                float inv0 = rsqrtf((float)keff);
                for (int m = 1; m <= keff; ++m) sY[m] = inv0;
                float d1 = sAl_[1] - th;
                if (fabsf(d1) < 1e-10f) d1 = (d1 >= 0.0f) ? 1e-10f : -1e-10f;
                sCp[1] = sBe_[1] / d1;
                sDp2[1] = sY[1] / d1;
                for (int m = 2; m <= keff; ++m) {
                    float den = sAl_[m] - th - sBe_[m - 1] * sCp[m - 1];
                    if (fabsf(den) < 1e-10f) den = (den >= 0.0f) ? 1e-10f : -1e-10f;
                    if (m < keff) sCp[m] = sBe_[m] / den;
                    sDp2[m] = (sY[m] - sBe_[m - 1] * sDp2[m - 1]) / den;
                }
                sY[keff] = sDp2[keff];
                for (int m = keff - 1; m >= 1; --m)
                    sY[m] = sDp2[m] - sCp[m] * sY[m + 1];
                float nn = 0.0f;
                for (int m = 1; m <= keff; ++m) nn += sY[m] * sY[m];
                float sc = rsqrtf(nn);
                for (int m = 1; m <= keff; ++m) sY[m] *= sc;
            }
        }
        WSYNC();
        float v = 0.0f;
        if (lane < NN)
            for (int m = 1; m <= keff; ++m) v += sY[m] * sQ2[m * QS + lane];
        {
            float nn = v * v;
            for (int off = 32; off > 0; off >>= 1) nn += __shfl_xor(nn, off);
            float av = fabsf(v);
            for (int off = 32; off > 0; off >>= 1) av = fmaxf(av, __shfl_xor(av, off));
            unsigned long long msk = __ballot((fabsf(v) == av) && (lane < NN));
            int fl = __ffsll((unsigned long long)msk) - 1;
            float sv = __shfl(v, fl);
            v *= ((sv >= 0.0f) ? 1.0f : -1.0f) * rsqrtf(nn);
        }
        xr3 = q0r; xr4 = v;
        if (lane < NN) {
            out[2501 + lane * 5 + 0] = xr0;
            out[2501 + lane * 5 + 1] = xr1;
            out[2501 + lane * 5 + 2] = xr2;
            out[2501 + lane * 5 + 3] = xr3;
            out[2501 + lane * 5 + 4] = xr4;
        }
    } else if (tid < 128) {
        // -------- wave 1: edges, counts (regs), prefix scan, CSR, ei out ----
        const int l = tid - 64;
        for (int t = l; t < ET; t += 64) {
            int s, d;
            if (t < E2) { s = gedge[t]; d = gedge[E2 + t]; }
            else        { s = t - E2;   d = t - E2; }
            sSrc[t] = s; sDst[t] = d;
        }
        WSYNC();
        int cnt = 0;
        if (l < NN)
            for (int e = 0; e < ET; ++e) cnt += (sDst[e] == l) ? 1 : 0;
        int inc = cnt;
#pragma unroll
        for (int off = 1; off < 64; off <<= 1) {
            int n = __shfl_up(inc, off);
            if (l >= off) inc += n;
        }
        int exc = inc - cnt;
        if (l < NN) sOff[l] = exc;
        if (l == NN - 1) sOff[NN] = inc;
        if (l < NN) {
            int pos = exc;
            for (int e = 0; e < ET; ++e)
                if (sDst[e] == l) { sSrcCsr[pos] = sSrc[e]; ++pos; }
        }
        for (int t = l; t < 2 * ET; t += 64) {
            int val = (t < ET) ? sSrc[t] : sDst[t - ET];
            out[2751 + t] = (float)val;
        }
    } else {
        // -------- waves 2-3: staging (issue all loads, then store) ----------
        const int t0 = tid - 128;
        float vW1  = w1 [t0 < 40 ? t0 : 39];
        float vAs1 = as1[t0 < 8  ? t0 : 7];
        float vAd1 = ad1[t0 < 8  ? t0 : 7];
        float vB1  = b1 [t0 < 8  ? t0 : 7];
        float vW2  = w2 [t0 < 40 ? t0 : 39];
        float vAs2 = as2[t0 < 5  ? t0 : 4];
        float vAd2 = ad2[t0 < 5  ? t0 : 4];
        float vB2  = b2 [t0 < 5  ? t0 : 4];
        float vMiw = miw[t0 < 75 ? t0 : 74];
        float vMib = mib[t0 < 15 ? t0 : 14];
        float vMow = mow[t0 < 25 ? t0 : 24];
        float vMob = mob[t0 < 5  ? t0 : 4];
        float vWq  = wq [t0 < 25 ? t0 : 24];
        float vBq  = bq [t0 < 5  ? t0 : 4];
        float vWk  = wk [t0 < 25 ? t0 : 24];
        float vBk  = bk [t0 < 5  ? t0 : 4];
        float vWv  = wv [t0 < 25 ? t0 : 24];
        float vBv  = bv [t0 < 5  ? t0 : 4];
        float vWs  = ws [t0 < 25 ? t0 : 24];
        float vBs  = bs [t0 < 5  ? t0 : 4];
        float vMb1 = mb1[t0 < 64 ? t0 : 63];
        float vMb2 = mb2[t0 < NN ? t0 : NN - 1];
        float vCw  = cw [t0 < NN ? t0 : NN - 1];
        float vCb  = cb[0];
        float vMsk = gmask[t0 < NN ? t0 : NN - 1];
        int ta = t0, tb2 = t0 + 128, tc = (t0 + 256 < 320) ? t0 + 256 : 319;
        float vM1a = mw1[(ta  / 5) * 250 + (ta  % 5)];
        float vM1b = mw1[(tb2 / 5) * 250 + (tb2 % 5)];
        float vM1c = mw1[(tc  / 5) * 250 + (tc  % 5)];
        const float4* m2 = (const float4*)mw2;
        float4 v2[7];
#pragma unroll
        for (int u = 0; u < 7; ++u) {
            int t = t0 + u * 128;
            v2[u] = m2[t < 800 ? t : 799];
        }
        if (t0 < 40) sW1[t0]  = vW1;
        if (t0 < 8)  { sAs1[t0] = vAs1; sAd1[t0] = vAd1; sB1[t0] = vB1; }
        if (t0 < 40) sW2[t0]  = vW2;
        if (t0 < 5)  { sAs2[t0] = vAs2; sAd2[t0] = vAd2; sB2[t0] = vB2; }
        if (t0 < 75) sMiw[t0] = vMiw;
        if (t0 < 15) sMib[t0] = vMib;
        if (t0 < 25) { sMow[t0] = vMow; sWq[t0] = vWq; sWk[t0] = vWk;
                       sWv[t0] = vWv;  sWsk[t0] = vWs; }
        if (t0 < 5)  { sMob[t0] = vMob; sBq[t0] = vBq; sBk[t0] = vBk;
                       sBv[t0] = vBv;  sBsk[t0] = vBs; }
        if (t0 < 64) sMb1[t0] = vMb1;
        if (t0 < NN) { sMb2[t0] = vMb2; sCw[t0] = vCw; sMask[t0] = vMsk; }
        if (t0 == 0) sCb0[0] = vCb;
        sMw1[ta]  = vM1a;
        sMw1[tb2] = vM1b;
        if (t0 + 256 < 320) sMw1[t0 + 256] = vM1c;
#pragma unroll
        for (int u = 0; u < 7; ++u) {
            int t = t0 + u * 128;
            if (t < 800) {
                int o = t >> 4, k4 = t & 15;
                *(float4*)&sMw2[o * MS + k4 * 4] = v2[u];
            }
        }
    }
    __syncthreads();   // join: weights + CSR visible to wave 0

    // ==== wave 0: fused GNN tail ====
    if (tid < 64) {
        const int lane = tid;
        const int c0 = (lane < NN) ? sOff[lane] : 0;
        const int c1 = (lane < NN) ? sOff[lane + 1] : 0;
        float* h8 = sS;
        // ---- P0: GAT1 linear + src coeff ----
        float adl = 0.0f;
        if (lane < NN) {
            float a = 0.0f;
#pragma unroll
            for (int o = 0; o < 8; ++o) {
                float acc = xr0 * sW1[o * 5 + 0] + xr1 * sW1[o * 5 + 1]
                          + xr2 * sW1[o * 5 + 2] + xr3 * sW1[o * 5 + 3]
                          + xr4 * sW1[o * 5 + 4];
                h8[lane * 8 + o] = acc;
                a   += acc * sAs1[o];
                adl += acc * sAd1[o];
            }
            sAs[lane] = a;
        }
        WSYNC();
        // ---- P1: GAT1 fused score+softmax+agg + GAT2 linear ----
        float adlB = 0.0f;
        if (lane < NN) {
            float su = 0.0f;
            float acc[8] = {0, 0, 0, 0, 0, 0, 0, 0};
            for (int c = c0; c < c1; ++c) {
                const int s2 = sSrcCsr[c];
                float sc = sAs[s2] + adl;
                sc = (sc > 0.0f) ? sc : 0.2f * sc;
                float p = __expf(sc);
                su += p;
                const float* hp = &h8[s2 * 8];
#pragma unroll
                for (int o = 0; o < 8; ++o) acc[o] += p * hp[o];
            }
            float inv = 1.0f / (su + 1e-16f);
            float o8r[8];
#pragma unroll
            for (int o = 0; o < 8; ++o) o8r[o] = fmaxf(sB1[o] + acc[o] * inv, 0.0f);
            float aB = 0.0f;
#pragma unroll
            for (int o = 0; o < 5; ++o) {
                float a2 = 0.0f;
#pragma unroll
                for (int k = 0; k < 8; ++k) a2 += o8r[k] * sW2[o * 8 + k];
                sB5h[lane * 5 + o] = a2;
                aB   += a2 * sAs2[o];
                adlB += a2 * sAd2[o];
            }
            sAsB[lane] = aB;
        }
        WSYNC();
        // ---- P2: GAT2 fused agg + MHA in-proj (packed k/v) ----
        float qr[5];
        if (lane < NN) {
            float su = 0.0f;
            float acc[5] = {0, 0, 0, 0, 0};
            for (int c = c0; c < c1; ++c) {
                const int s2 = sSrcCsr[c];
                float sc = sAsB[s2] + adlB;
                sc = (sc > 0.0f) ? sc : 0.2f * sc;
                float p = __expf(sc);
                su += p;
                const float* hp = &sB5h[s2 * 5];
#pragma unroll
                for (int o = 0; o < 5; ++o) acc[o] += p * hp[o];
            }
            float inv = 1.0f / (su + 1e-16f);
            float hr[5];
#pragma unroll
            for (int o = 0; o < 5; ++o) hr[o] = sB2[o] + acc[o] * inv;
#pragma unroll
            for (int o = 0; o < 5; ++o) {
                float q_ = sMib[o], k_ = sMib[o + 5], v_ = sMib[o + 10];
#pragma unroll
                for (int k = 0; k < 5; ++k) {
                    q_ += hr[k] * sMiw[o * 5 + k];
                    k_ += hr[k] * sMiw[(o + 5) * 5 + k];
                    v_ += hr[k] * sMiw[(o + 10) * 5 + k];
                }
                qr[o] = q_;
                sKV[lane * 16 + o]     = k_;
                sKV[lane * 16 + 8 + o] = v_;
            }
        }
        WSYNC();
        // ---- P3: MHA single-pass attn (float4 packed reads) + TC linear ----
        float tq[5], skip[5];
        if (lane < NN) {
            float su = 0.0f;
            float a5[5] = {0, 0, 0, 0, 0};
            for (int j = 0; j < NN; ++j) {
                const float* row = &sKV[j * 16];
                float4 k4 = *(const float4*)row;
                float  kk = row[4];
                float d = qr[0] * k4.x + qr[1] * k4.y + qr[2] * k4.z
                        + qr[3] * k4.w + qr[4] * kk;
                float p = __expf(d * inv_sqrt5);
                su += p;
                float4 v4 = *(const float4*)(row + 8);
                float  vv = row[12];
                a5[0] += p * v4.x; a5[1] += p * v4.y; a5[2] += p * v4.z;
                a5[3] += p * v4.w; a5[4] += p * vv;
            }
            float inv = 1.0f / su;
#pragma unroll
            for (int f = 0; f < 5; ++f) a5[f] *= inv;
            float hm[5];
#pragma unroll
            for (int o = 0; o < 5; ++o) {
                float acc = sMob[o];
#pragma unroll
                for (int k = 0; k < 5; ++k) acc += a5[k] * sMow[o * 5 + k];
                hm[o] = acc;
            }
#pragma unroll
            for (int o = 0; o < 5; ++o) {
                float q_ = sBq[o], k_ = sBk[o], v_ = sBv[o], s_ = sBsk[o];
#pragma unroll
                for (int k = 0; k < 5; ++k) {
                    q_ += hm[k] * sWq[o * 5 + k];
                    k_ += hm[k] * sWk[o * 5 + k];
                    v_ += hm[k] * sWv[o * 5 + k];
                    s_ += hm[k] * sWsk[o * 5 + k];
                }
                tq[o] = q_;
                sTKV[lane * 16 + o]     = k_;
                sTKV[lane * 16 + 8 + o] = v_;
                skip[o] = s_;
            }
        }
        WSYNC();
        // ---- P4: TC fused score+softmax+agg + skip (packed reads) ----
        if (lane < NN) {
            float su = 0.0f;
            float acc[5] = {0, 0, 0, 0, 0};
            for (int c = c0; c < c1; ++c) {
                const int s2 = sSrcCsr[c];
                const float* row = &sTKV[s2 * 16];
                float4 k4 = *(const float4*)row;
                float  kk = row[4];
                float d = tq[0] * k4.x + tq[1] * k4.y + tq[2] * k4.z
                        + tq[3] * k4.w + tq[4] * kk;
                float p = __expf(d * inv_sqrt5);
                su += p;
                float4 v4 = *(const float4*)(row + 8);
                float  vv = row[12];
                acc[0] += p * v4.x; acc[1] += p * v4.y; acc[2] += p * v4.z;
                acc[3] += p * v4.w; acc[4] += p * vv;
            }
            float inv = 1.0f / (su + 1e-16f);
#pragma unroll
            for (int o = 0; o < 5; ++o) sTo[lane * 5 + o] = skip[o] + acc[o] * inv;
        }
        WSYNC();
        // ---- P5: MLP1 (lane = hidden unit) ----
        {
            float wv5[5];
#pragma unroll
            for (int k = 0; k < 5; ++k) wv5[k] = sMw1[lane * 5 + k];
            const float bo = sMb1[lane];
            for (int i = 0; i < NN; ++i) {
                float acc = bo;
#pragma unroll
                for (int k = 0; k < 5; ++k) acc += sTo[i * 5 + k] * wv5[k];
                sS[i * 64 + lane] = fmaxf(acc, 0.0f);
            }
        }
    }
    __syncthreads();

    // ---------------- MLP2 + fused critic (4 waves) ----------------
    float part = 0.0f;
    for (int t = tid; t < NN * NN; t += NTHR) {
        int i = t / NN, j = t - i * NN;
        const float4* sp4 = (const float4*)&sS[i * 64];
        const float4* wp4 = (const float4*)&sMw2[j * MS];
        float a0 = 0.0f, a1 = 0.0f, a2 = 0.0f, a3 = 0.0f;
        for (int k = 0; k < 16; ++k) {
            float4 a = sp4[k], b = wp4[k];
            a0 += a.x * b.x; a1 += a.y * b.y;
            a2 += a.z * b.z; a3 += a.w * b.w;
        }
        float acc = sMb2[j] + (a0 + a1) + (a2 + a3);
        out[t] = acc * sMask[j];
        part += acc * sCw[j];
    }
    for (int off = 32; off > 0; off >>= 1) part += __shfl_xor(part, off);
    if ((tid & 63) == 0) sred[tid >> 6] = part;
    __syncthreads();
    if (tid == 0)
        out[2500] = (sred[0] + sred[1] + sred[2] + sred[3]) * (1.0f / NN) + sCb0[0];
}

extern "C" void kernel_launch(void* const* d_in, const int* in_sizes, int n_in,
                              void* d_out, int out_size, void* d_ws, size_t ws_size,
                              hipStream_t stream) {
    (void)in_sizes; (void)n_in; (void)d_ws; (void)ws_size; (void)out_size;
    opn_kernel<<<1, NTHR, 0, stream>>>(
        (const float*)d_in[0], (const int*)d_in[1], (const float*)d_in[2],
        (const float*)d_in[3], (const float*)d_in[4], (const float*)d_in[5], (const float*)d_in[6],
        (const float*)d_in[7], (const float*)d_in[8], (const float*)d_in[9], (const float*)d_in[10],
        (const float*)d_in[11], (const float*)d_in[12], (const float*)d_in[13], (const float*)d_in[14],
        (const float*)d_in[15], (const float*)d_in[16], (const float*)d_in[17], (const float*)d_in[18],
        (const float*)d_in[19], (const float*)d_in[20], (const float*)d_in[21], (const float*)d_in[22],
        (const float*)d_in[23], (const float*)d_in[24], (const float*)d_in[25], (const float*)d_in[26],
        (const float*)d_in[27], (const float*)d_in[28],
        (float*)d_out);
}

// Round 16
// 60.660 us; speedup vs baseline: 1.2635x; 1.0350x over previous
//
#include <hip/hip_runtime.h>
#include <math.h>

#define NN 50
#define E2 400
#define ET 450
#define NTHR 256
#define KL 8             // Lanczos iterations
#define QS 52            // padded row stride (16B-aligned rows)
#define MS 68            // padded sMw2 row stride

// Intra-wave LDS handoff fence: drain LDS ops, forbid compiler reordering.
#define WSYNC() do { asm volatile("s_waitcnt lgkmcnt(0)" ::: "memory"); \
                     __builtin_amdgcn_sched_barrier(0); } while (0)

__global__ __launch_bounds__(NTHR, 1) void opn_kernel(
    const float* __restrict__ gx, const int* __restrict__ gedge,
    const float* __restrict__ gmask,
    const float* __restrict__ w1, const float* __restrict__ as1,
    const float* __restrict__ ad1, const float* __restrict__ b1,
    const float* __restrict__ w2, const float* __restrict__ as2,
    const float* __restrict__ ad2, const float* __restrict__ b2,
    const float* __restrict__ miw, const float* __restrict__ mib,
    const float* __restrict__ mow, const float* __restrict__ mob,
    const float* __restrict__ wq, const float* __restrict__ bq,
    const float* __restrict__ wk, const float* __restrict__ bk,
    const float* __restrict__ wv, const float* __restrict__ bv,
    const float* __restrict__ ws, const float* __restrict__ bs,
    const float* __restrict__ mw1, const float* __restrict__ mb1,
    const float* __restrict__ mw2, const float* __restrict__ mb2,
    const float* __restrict__ cw, const float* __restrict__ cb,
    float* __restrict__ out)
{
    const int tid = threadIdx.x;

    __shared__ alignas(16) float sM[NN * QS];        // adjacency -> Laplacian (in place)
    __shared__ alignas(16) float sS[3200];           // GAT1 h8 -> MLP hid64
    __shared__ alignas(16) float sQ2[(KL + 2) * QS]; // Lanczos vectors
    __shared__ alignas(16) float sdis[QS];
    __shared__ float sAl_[KL + 2];
    __shared__ float sBe_[KL + 2];
    __shared__ float sY[KL + 2];
    __shared__ float sCp[KL + 2];
    __shared__ float sDp2[KL + 2];
    __shared__ float sB5h[NN * 5];   // GAT2 h5
    __shared__ alignas(16) float sKV[NN * 16];  // MHA k@0-4, v@8-12
    __shared__ alignas(16) float sTKV[NN * 16]; // TC  k@0-4, v@8-12
    __shared__ float sTo[NN * 5];    // TC out
    __shared__ int   sSrc[ET];
    __shared__ int   sDst[ET];
    __shared__ int   sSrcCsr[ET];
    __shared__ float sAs[NN];        // GAT1 src coeffs
    __shared__ float sAsB[NN];       // GAT2 src coeffs
    __shared__ float sred[4];
    __shared__ int   sOff[NN + 1];
    // staged weights (filled by waves 2-3)
    __shared__ float sW1[40], sAs1[8], sAd1[8], sB1[8];
    __shared__ float sW2[40], sAs2[5], sAd2[5], sB2[5];
    __shared__ float sMiw[75], sMib[15], sMow[25], sMob[5];
    __shared__ float sWq[25], sBq[5], sWk[25], sBk[5];
    __shared__ float sWv[25], sBv[5], sWsk[25], sBsk[5];
    __shared__ float sMw1[320], sMb1[64];
    __shared__ alignas(16) float sMw2[NN * MS];
    __shared__ float sMb2[NN], sCw[NN], sCb0[1], sMask[NN];

    const float inv_sqrt5 = 0.4472135954999579f;
    float xr0 = 0, xr1 = 0, xr2 = 0, xr3 = 0, xr4 = 0;   // x_combined row (wave 0)
    int keffr = KL;

    // ======== parallel section: zero shared barriers ========
    if (tid < 64) {
        // -------- wave 0: adjacency -> Laplacian (in place) -> Lanczos ----
        const int lane = tid;
        {   // early global loads
            int gi = (lane < NN) ? lane : NN - 1;
            xr0 = gx[gi * 3 + 0]; xr1 = gx[gi * 3 + 1]; xr2 = gx[gi * 3 + 2];
        }
        int es[7], ed[7];
#pragma unroll
        for (int u = 0; u < 7; ++u) {
            int e = lane + u * 64;
            int ec = (e < E2) ? e : E2 - 1;
            es[u] = gedge[ec]; ed[u] = gedge[E2 + ec];
        }
        {   // float4 zero of padded adjacency (650 float4)
            float4* z4 = (float4*)sM;
            const float4 z = {0, 0, 0, 0};
            for (int t = lane; t < (NN * QS) / 4; t += 64) z4[t] = z;
        }
        WSYNC();
#pragma unroll
        for (int u = 0; u < 7; ++u) {
            int e = lane + u * 64;
            if (e < E2) atomicAdd(&sM[es[u] * QS + ed[u]], 1.0f);
        }
        WSYNC();
        // rowsum: 13 float4 reads of OWN row (lane-local, padding is zero)
        float dsum = 0.0f;
        if (lane < NN) {
            const float4* rp4 = (const float4*)&sM[lane * QS];
            float a0 = 0, a1 = 0, a2 = 0, a3 = 0;
#pragma unroll
            for (int k = 0; k < 13; ++k) {
                float4 r = rp4[k];
                a0 += r.x; a1 += r.y; a2 += r.z; a3 += r.w;
            }
            dsum = (a0 + a1) + (a2 + a3);
        }
        float disl = (dsum > 0.0f) ? (1.0f / sqrtf(fmaxf(dsum, 1e-12f))) : 0.0f;
        sdis[lane] = (lane < NN) ? disl : 0.0f;
        if (lane < 13) { if (50 + lane < QS) sdis[50 + lane] = 0.0f; }
        WSYNC();   // sdis visible (broadcast reads below)
        // L build in place: lane-local float4 RMW of own row
        if (lane < NN) {
            float4* rp4 = (float4*)&sM[lane * QS];
            const float4* d4 = (const float4*)sdis;
#pragma unroll
            for (int k = 0; k < 13; ++k) {
                float4 a = rp4[k], dd = d4[k];
                int col = 4 * k;
                a.x = ((lane == col)     ? 1.0f : 0.0f) - disl * a.x * dd.x;
                a.y = ((lane == col + 1) ? 1.0f : 0.0f) - disl * a.y * dd.y;
                a.z = ((lane == col + 2) ? 1.0f : 0.0f) - disl * a.z * dd.z;
                a.w = ((lane == col + 3) ? 1.0f : 0.0f) - disl * a.w * dd.w;
                rp4[k] = a;
            }
        }
        // u0 normalize + deterministic q1
        float q0r, qprev = 0.0f, qcur;
        {
            float q0 = (lane < NN) ? sqrtf(dsum) : 0.0f;
            float nn = q0 * q0;
            for (int off = 32; off > 0; off >>= 1) nn += __shfl_xor(nn, off);
            q0 *= rsqrtf(nn);
            unsigned u = (unsigned)lane * 2654435761u + 12345u;
            u ^= u >> 13; u *= 2246822519u; u ^= u >> 11;
            float q1 = (lane < NN) ? ((float)(u & 0xFFFF) * (1.0f / 65536.0f) - 0.5f) : 0.0f;
            for (int pass = 0; pass < 2; ++pass) {
                float d = q0 * q1;
                for (int off = 32; off > 0; off >>= 1) d += __shfl_xor(d, off);
                q1 -= d * q0;
            }
            float n1 = q1 * q1;
            for (int off = 32; off > 0; off >>= 1) n1 += __shfl_xor(n1, off);
            q1 *= rsqrtf(n1);
            q0r = q0; qcur = q1;
            if (lane < NN) { sQ2[lane] = q0; sQ2[QS + lane] = q1; }
            WSYNC();          // q rows visible before matvec
        }
        // -------- 3-term Lanczos on B = 2I - L (own-row float4 matvec) -----
        for (int j = 1; j <= KL; ++j) {
            const float* qp = &sQ2[j * QS];
            const float4* qp4 = (const float4*)qp;
            float w = 0.0f;
            if (lane < NN) {
                const float4* rp4 = (const float4*)&sM[lane * QS];
                float a0 = 0.0f, a1 = 0.0f, a2 = 0.0f, a3 = 0.0f;
#pragma unroll
                for (int k = 0; k < 13; ++k) {
                    float4 r = rp4[k], q = qp4[k];
                    a0 += r.x * q.x; a1 += r.y * q.y;
                    a2 += r.z * q.z; a3 += r.w * q.w;
                }
                w = 2.0f * qcur - ((a0 + a1) + (a2 + a3));
            }
            float c0 = q0r * w, c1 = qprev * w, ca = qcur * w;
#pragma unroll
            for (int off = 32; off > 0; off >>= 1) {
                c0 += __shfl_xor(c0, off);
                c1 += __shfl_xor(c1, off);
                ca += __shfl_xor(ca, off);
            }
            w -= c0 * q0r + c1 * qprev + ca * qcur;
            float nn2 = w * w;
#pragma unroll
            for (int off = 32; off > 0; off >>= 1) nn2 += __shfl_xor(nn2, off);
            float beta = sqrtf(nn2);
            if (lane == 0) { sAl_[j] = ca; sBe_[j] = beta; }
            if (j < KL) {
                if (beta > 1e-10f) {
                    qprev = qcur;
                    qcur = w * (1.0f / beta);
                    if (lane < NN) sQ2[(j + 1) * QS + lane] = qcur;
                    WSYNC();
                } else { keffr = j; break; }     // beta lane-uniform
            }
        }
        WSYNC();
        // -------- extraction: bisection (3 rounds) + Thomas + Fiedler ------
        const int keff = keffr;
        float lo = 1e30f, hi = -1e30f;
        for (int m = 1; m <= keff; ++m) {
            float r = ((m > 1) ? fabsf(sBe_[m - 1]) : 0.0f)
                    + ((m < keff) ? fabsf(sBe_[m]) : 0.0f);
            lo = fminf(lo, sAl_[m] - r);
            hi = fmaxf(hi, sAl_[m] + r);
        }
        for (int round = 0; round < 3; ++round) {
            float h = (hi - lo) * (1.0f / 65.0f);
            float x = lo + (float)(lane + 1) * h;
            int cnt = 0;
            float d = sAl_[1] - x;
            if (d < 0.0f) cnt++;
            for (int m = 2; m <= keff; ++m) {
                float b = sBe_[m - 1];
                float dd = (fabsf(d) < 1e-20f) ? ((d >= 0.0f) ? 1e-20f : -1e-20f) : d;
                d = sAl_[m] - x - b * b / dd;
                if (d < 0.0f) cnt++;
            }
            unsigned long long msk = __ballot(cnt >= keff);
            int f = (msk == 0ULL) ? 64 : (__ffsll((unsigned long long)msk) - 1);
            float nlo = (f == 0) ? lo : (lo + (float)f * h);
            float nhi = (f == 64) ? hi : (lo + (float)(f + 1) * h);
            lo = nlo; hi = nhi;
        }
        const float th = 0.5f * (lo + hi);
        if (lane == 0) {
            if (keff == 1) {
                sY[1] = 1.0f;
            } else {
                float inv0 = rsqrtf((float)keff);
                for (int m = 1; m <= keff; ++m) sY[m] = inv0;
                float d1 = sAl_[1] - th;
                if (fabsf(d1) < 1e-10f) d1 = (d1 >= 0.0f) ? 1e-10f : -1e-10f;
                sCp[1] = sBe_[1] / d1;
                sDp2[1] = sY[1] / d1;
                for (int m = 2; m <= keff; ++m) {
                    float den = sAl_[m] - th - sBe_[m - 1] * sCp[m - 1];
                    if (fabsf(den) < 1e-10f) den = (den >= 0.0f) ? 1e-10f : -1e-10f;
                    if (m < keff) sCp[m] = sBe_[m] / den;
                    sDp2[m] = (sY[m] - sBe_[m - 1] * sDp2[m - 1]) / den;
                }
                sY[keff] = sDp2[keff];
                for (int m = keff - 1; m >= 1; --m)
                    sY[m] = sDp2[m] - sCp[m] * sY[m + 1];
                float nn = 0.0f;
                for (int m = 1; m <= keff; ++m) nn += sY[m] * sY[m];
                float sc = rsqrtf(nn);
                for (int m = 1; m <= keff; ++m) sY[m] *= sc;
            }
        }
        WSYNC();
        float v = 0.0f;
        if (lane < NN)
            for (int m = 1; m <= keff; ++m) v += sY[m] * sQ2[m * QS + lane];
        {
            float nn = v * v;
            for (int off = 32; off > 0; off >>= 1) nn += __shfl_xor(nn, off);
            float av = fabsf(v);
            for (int off = 32; off > 0; off >>= 1) av = fmaxf(av, __shfl_xor(av, off));
            unsigned long long msk = __ballot((fabsf(v) == av) && (lane < NN));
            int fl = __ffsll((unsigned long long)msk) - 1;
            float sv = __shfl(v, fl);
            v *= ((sv >= 0.0f) ? 1.0f : -1.0f) * rsqrtf(nn);
        }
        xr3 = q0r; xr4 = v;
        if (lane < NN) {
            out[2501 + lane * 5 + 0] = xr0;
            out[2501 + lane * 5 + 1] = xr1;
            out[2501 + lane * 5 + 2] = xr2;
            out[2501 + lane * 5 + 3] = xr3;
            out[2501 + lane * 5 + 4] = xr4;
        }
    } else if (tid < 128) {
        // -------- wave 1: edges, ei out (early), counts, scan, CSR ----------
        const int l = tid - 64;
        for (int t = l; t < ET; t += 64) {
            int s, d;
            if (t < E2) { s = gedge[t]; d = gedge[E2 + t]; }
            else        { s = t - E2;   d = t - E2; }
            sSrc[t] = s; sDst[t] = d;
            out[2751 + t] = (float)s;          // ei row 0 (from regs, no LDS dep)
            out[2751 + ET + t] = (float)d;     // ei row 1
        }
        WSYNC();
        int cnt = 0;
        if (l < NN)
            for (int e = 0; e < ET; ++e) cnt += (sDst[e] == l) ? 1 : 0;
        int inc = cnt;
#pragma unroll
        for (int off = 1; off < 64; off <<= 1) {
            int n = __shfl_up(inc, off);
            if (l >= off) inc += n;
        }
        int exc = inc - cnt;
        if (l < NN) sOff[l] = exc;
        if (l == NN - 1) sOff[NN] = inc;
        if (l < NN) {
            int pos = exc;
            for (int e = 0; e < ET; ++e)
                if (sDst[e] == l) { sSrcCsr[pos] = sSrc[e]; ++pos; }
        }
    } else {
        // -------- waves 2-3: staging (issue all loads, then store) ----------
        const int t0 = tid - 128;
        float vW1  = w1 [t0 < 40 ? t0 : 39];
        float vAs1 = as1[t0 < 8  ? t0 : 7];
        float vAd1 = ad1[t0 < 8  ? t0 : 7];
        float vB1  = b1 [t0 < 8  ? t0 : 7];
        float vW2  = w2 [t0 < 40 ? t0 : 39];
        float vAs2 = as2[t0 < 5  ? t0 : 4];
        float vAd2 = ad2[t0 < 5  ? t0 : 4];
        float vB2  = b2 [t0 < 5  ? t0 : 4];
        float vMiw = miw[t0 < 75 ? t0 : 74];
        float vMib = mib[t0 < 15 ? t0 : 14];
        float vMow = mow[t0 < 25 ? t0 : 24];
        float vMob = mob[t0 < 5  ? t0 : 4];
        float vWq  = wq [t0 < 25 ? t0 : 24];
        float vBq  = bq [t0 < 5  ? t0 : 4];
        float vWk  = wk [t0 < 25 ? t0 : 24];
        float vBk  = bk [t0 < 5  ? t0 : 4];
        float vWv  = wv [t0 < 25 ? t0 : 24];
        float vBv  = bv [t0 < 5  ? t0 : 4];
        float vWs  = ws [t0 < 25 ? t0 : 24];
        float vBs  = bs [t0 < 5  ? t0 : 4];
        float vMb1 = mb1[t0 < 64 ? t0 : 63];
        float vMb2 = mb2[t0 < NN ? t0 : NN - 1];
        float vCw  = cw [t0 < NN ? t0 : NN - 1];
        float vCb  = cb[0];
        float vMsk = gmask[t0 < NN ? t0 : NN - 1];
        int ta = t0, tb2 = t0 + 128, tc = (t0 + 256 < 320) ? t0 + 256 : 319;
        float vM1a = mw1[(ta  / 5) * 250 + (ta  % 5)];
        float vM1b = mw1[(tb2 / 5) * 250 + (tb2 % 5)];
        float vM1c = mw1[(tc  / 5) * 250 + (tc  % 5)];
        const float4* m2 = (const float4*)mw2;
        float4 v2[7];
#pragma unroll
        for (int u = 0; u < 7; ++u) {
            int t = t0 + u * 128;
            v2[u] = m2[t < 800 ? t : 799];
        }
        if (t0 < 40) sW1[t0]  = vW1;
        if (t0 < 8)  { sAs1[t0] = vAs1; sAd1[t0] = vAd1; sB1[t0] = vB1; }
        if (t0 < 40) sW2[t0]  = vW2;
        if (t0 < 5)  { sAs2[t0] = vAs2; sAd2[t0] = vAd2; sB2[t0] = vB2; }
        if (t0 < 75) sMiw[t0] = vMiw;
        if (t0 < 15) sMib[t0] = vMib;
        if (t0 < 25) { sMow[t0] = vMow; sWq[t0] = vWq; sWk[t0] = vWk;
                       sWv[t0] = vWv;  sWsk[t0] = vWs; }
        if (t0 < 5)  { sMob[t0] = vMob; sBq[t0] = vBq; sBk[t0] = vBk;
                       sBv[t0] = vBv;  sBsk[t0] = vBs; }
        if (t0 < 64) sMb1[t0] = vMb1;
        if (t0 < NN) { sMb2[t0] = vMb2; sCw[t0] = vCw; sMask[t0] = vMsk; }
        if (t0 == 0) sCb0[0] = vCb;
        sMw1[ta]  = vM1a;
        sMw1[tb2] = vM1b;
        if (t0 + 256 < 320) sMw1[t0 + 256] = vM1c;
#pragma unroll
        for (int u = 0; u < 7; ++u) {
            int t = t0 + u * 128;
            if (t < 800) {
                int o = t >> 4, k4 = t & 15;
                *(float4*)&sMw2[o * MS + k4 * 4] = v2[u];
            }
        }
    }
    __syncthreads();   // join: weights + CSR visible to wave 0

    // ==== wave 0: fused GNN tail ====
    if (tid < 64) {
        const int lane = tid;
        const int c0 = (lane < NN) ? sOff[lane] : 0;
        const int c1 = (lane < NN) ? sOff[lane + 1] : 0;
        float* h8 = sS;
        // ---- P0: GAT1 linear + src coeff ----
        float adl = 0.0f;
        if (lane < NN) {
            float a = 0.0f;
#pragma unroll
            for (int o = 0; o < 8; ++o) {
                float acc = xr0 * sW1[o * 5 + 0] + xr1 * sW1[o * 5 + 1]
                          + xr2 * sW1[o * 5 + 2] + xr3 * sW1[o * 5 + 3]
                          + xr4 * sW1[o * 5 + 4];
                h8[lane * 8 + o] = acc;
                a   += acc * sAs1[o];
                adl += acc * sAd1[o];
            }
            sAs[lane] = a;
        }
        WSYNC();
        // ---- P1: GAT1 fused score+softmax+agg + GAT2 linear ----
        float adlB = 0.0f;
        if (lane < NN) {
            float su = 0.0f;
            float acc[8] = {0, 0, 0, 0, 0, 0, 0, 0};
            for (int c = c0; c < c1; ++c) {
                const int s2 = sSrcCsr[c];
                float sc = sAs[s2] + adl;
                sc = (sc > 0.0f) ? sc : 0.2f * sc;
                float p = __expf(sc);
                su += p;
                const float* hp = &h8[s2 * 8];
#pragma unroll
                for (int o = 0; o < 8; ++o) acc[o] += p * hp[o];
            }
            float inv = 1.0f / (su + 1e-16f);
            float o8r[8];
#pragma unroll
            for (int o = 0; o < 8; ++o) o8r[o] = fmaxf(sB1[o] + acc[o] * inv, 0.0f);
            float aB = 0.0f;
#pragma unroll
            for (int o = 0; o < 5; ++o) {
                float a2 = 0.0f;
#pragma unroll
                for (int k = 0; k < 8; ++k) a2 += o8r[k] * sW2[o * 8 + k];
                sB5h[lane * 5 + o] = a2;
                aB   += a2 * sAs2[o];
                adlB += a2 * sAd2[o];
            }
            sAsB[lane] = aB;
        }
        WSYNC();
        // ---- P2: GAT2 fused agg + MHA in-proj (packed k/v) ----
        float qr[5];
        if (lane < NN) {
            float su = 0.0f;
            float acc[5] = {0, 0, 0, 0, 0};
            for (int c = c0; c < c1; ++c) {
                const int s2 = sSrcCsr[c];
                float sc = sAsB[s2] + adlB;
                sc = (sc > 0.0f) ? sc : 0.2f * sc;
                float p = __expf(sc);
                su += p;
                const float* hp = &sB5h[s2 * 5];
#pragma unroll
                for (int o = 0; o < 5; ++o) acc[o] += p * hp[o];
            }
            float inv = 1.0f / (su + 1e-16f);
            float hr[5];
#pragma unroll
            for (int o = 0; o < 5; ++o) hr[o] = sB2[o] + acc[o] * inv;
#pragma unroll
            for (int o = 0; o < 5; ++o) {
                float q_ = sMib[o], k_ = sMib[o + 5], v_ = sMib[o + 10];
#pragma unroll
                for (int k = 0; k < 5; ++k) {
                    q_ += hr[k] * sMiw[o * 5 + k];
                    k_ += hr[k] * sMiw[(o + 5) * 5 + k];
                    v_ += hr[k] * sMiw[(o + 10) * 5 + k];
                }
                qr[o] = q_;
                sKV[lane * 16 + o]     = k_;
                sKV[lane * 16 + 8 + o] = v_;
            }
        }
        WSYNC();
        // ---- P3: MHA single-pass attn (float4 packed reads) + TC linear ----
        float tq[5], skip[5];
        if (lane < NN) {
            float su = 0.0f;
            float a5[5] = {0, 0, 0, 0, 0};
            for (int j = 0; j < NN; ++j) {
                const float* row = &sKV[j * 16];
                float4 k4 = *(const float4*)row;
                float  kk = row[4];
                float d = qr[0] * k4.x + qr[1] * k4.y + qr[2] * k4.z
                        + qr[3] * k4.w + qr[4] * kk;
                float p = __expf(d * inv_sqrt5);
                su += p;
                float4 v4 = *(const float4*)(row + 8);
                float  vv = row[12];
                a5[0] += p * v4.x; a5[1] += p * v4.y; a5[2] += p * v4.z;
                a5[3] += p * v4.w; a5[4] += p * vv;
            }
            float inv = 1.0f / su;
#pragma unroll
            for (int f = 0; f < 5; ++f) a5[f] *= inv;
            float hm[5];
#pragma unroll
            for (int o = 0; o < 5; ++o) {
                float acc = sMob[o];
#pragma unroll
                for (int k = 0; k < 5; ++k) acc += a5[k] * sMow[o * 5 + k];
                hm[o] = acc;
            }
#pragma unroll
            for (int o = 0; o < 5; ++o) {
                float q_ = sBq[o], k_ = sBk[o], v_ = sBv[o], s_ = sBsk[o];
#pragma unroll
                for (int k = 0; k < 5; ++k) {
                    q_ += hm[k] * sWq[o * 5 + k];
                    k_ += hm[k] * sWk[o * 5 + k];
                    v_ += hm[k] * sWv[o * 5 + k];
                    s_ += hm[k] * sWsk[o * 5 + k];
                }
                tq[o] = q_;
                sTKV[lane * 16 + o]     = k_;
                sTKV[lane * 16 + 8 + o] = v_;
                skip[o] = s_;
            }
        }
        WSYNC();
        // ---- P4: TC fused score+softmax+agg + skip (packed reads) ----
        if (lane < NN) {
            float su = 0.0f;
            float acc[5] = {0, 0, 0, 0, 0};
            for (int c = c0; c < c1; ++c) {
                const int s2 = sSrcCsr[c];
                const float* row = &sTKV[s2 * 16];
                float4 k4 = *(const float4*)row;
                float  kk = row[4];
                float d = tq[0] * k4.x + tq[1] * k4.y + tq[2] * k4.z
                        + tq[3] * k4.w + tq[4] * kk;
                float p = __expf(d * inv_sqrt5);
                su += p;
                float4 v4 = *(const float4*)(row + 8);
                float  vv = row[12];
                acc[0] += p * v4.x; acc[1] += p * v4.y; acc[2] += p * v4.z;
                acc[3] += p * v4.w; acc[4] += p * vv;
            }
            float inv = 1.0f / (su + 1e-16f);
#pragma unroll
            for (int o = 0; o < 5; ++o) sTo[lane * 5 + o] = skip[o] + acc[o] * inv;
        }
        WSYNC();
        // ---- P5: MLP1 (lane = hidden unit) ----
        {
            float wv5[5];
#pragma unroll
            for (int k = 0; k < 5; ++k) wv5[k] = sMw1[lane * 5 + k];
            const float bo = sMb1[lane];
            for (int i = 0; i < NN; ++i) {
                float acc = bo;
#pragma unroll
                for (int k = 0; k < 5; ++k) acc += sTo[i * 5 + k] * wv5[k];
                sS[i * 64 + lane] = fmaxf(acc, 0.0f);
            }
        }
    }
    __syncthreads();

    // ---------------- MLP2 + fused critic (4 waves) ----------------
    float part = 0.0f;
    for (int t = tid; t < NN * NN; t += NTHR) {
        int i = t / NN, j = t - i * NN;
        const float4* sp4 = (const float4*)&sS[i * 64];
        const float4* wp4 = (const float4*)&sMw2[j * MS];
        float a0 = 0.0f, a1 = 0.0f, a2 = 0.0f, a3 = 0.0f;
        for (int k = 0; k < 16; ++k) {
            float4 a = sp4[k], b = wp4[k];
            a0 += a.x * b.x; a1 += a.y * b.y;
            a2 += a.z * b.z; a3 += a.w * b.w;
        }
        float acc = sMb2[j] + (a0 + a1) + (a2 + a3);
        out[t] = acc * sMask[j];
        part += acc * sCw[j];
    }
    for (int off = 32; off > 0; off >>= 1) part += __shfl_xor(part, off);
    if ((tid & 63) == 0) sred[tid >> 6] = part;
    __syncthreads();
    if (tid == 0)
        out[2500] = (sred[0] + sred[1] + sred[2] + sred[3]) * (1.0f / NN) + sCb0[0];
}

extern "C" void kernel_launch(void* const* d_in, const int* in_sizes, int n_in,
                              void* d_out, int out_size, void* d_ws, size_t ws_size,
                              hipStream_t stream) {
    (void)in_sizes; (void)n_in; (void)d_ws; (void)ws_size; (void)out_size;
    opn_kernel<<<1, NTHR, 0, stream>>>(
        (const float*)d_in[0], (const int*)d_in[1], (const float*)d_in[2],
        (const float*)d_in[3], (const float*)d_in[4], (const float*)d_in[5], (const float*)d_in[6],
        (const float*)d_in[7], (const float*)d_in[8], (const float*)d_in[9], (const float*)d_in[10],
        (const float*)d_in[11], (const float*)d_in[12], (const float*)d_in[13], (const float*)d_in[14],
        (const float*)d_in[15], (const float*)d_in[16], (const float*)d_in[17], (const float*)d_in[18],
        (const float*)d_in[19], (const float*)d_in[20], (const float*)d_in[21], (const float*)d_in[22],
        (const float*)d_in[23], (const float*)d_in[24], (const float*)d_in[25], (const float*)d_in[26],
        (const float*)d_in[27], (const float*)d_in[28],
        (float*)d_out);
}